// Round 1
// baseline (343.739 us; speedup 1.0000x reference)
//
#include <hip/hip_runtime.h>
#include <stdint.h>

// Problem constants: B=4, C=128, H=W=128, N=9, OC=256, stride=1
#define CIN   128
#define HDIM  128
#define WDIM  128
#define HWSZ  16384
#define NP    9
#define OCH   256
#define KDIM  1152

typedef __bf16 bf16_t;
typedef __bf16 bf16x8 __attribute__((ext_vector_type(8)));
typedef float  f32x4  __attribute__((ext_vector_type(4)));
struct __attribute__((packed, aligned(4))) F2 { float x, y; };

// XCD-locality swizzle (grid=512): give XCD k a contiguous band of 64
// logical (b,ii) blocks so its 4MB L2 holds the x rows it needs.
__device__ __forceinline__ int swz(int hw) { return (hw & 7) * 64 + (hw >> 3); }

// async global->LDS, 16B per lane. LDS dest must be wave-uniform base + lane*16.
__device__ __forceinline__ void gll16(const void* g, void* l) {
  __builtin_amdgcn_global_load_lds(
      (const __attribute__((address_space(1))) void*)g,
      (__attribute__((address_space(3))) void*)l, 16, 0, 0);
}

// ---------------------------------------------------------------------------
// B_T[o][k] bf16, k = n*128 + c  (= w_conv[o][c][n])
// ---------------------------------------------------------------------------
__global__ void k_bt(const float* __restrict__ wc, bf16_t* __restrict__ bt) {
  int c = threadIdx.x, n = blockIdx.x, o = blockIdx.y;
  bt[o * KDIM + n * 128 + c] = (bf16_t)wc[(o * CIN + c) * NP + n];
}

// ---------------------------------------------------------------------------
// Offset conv (3x3 pad 1, 128->18) in PURE FP32 + bilinear meta.
// fp32 is REQUIRED: bilinear sampling is discontinuous at borders (clamped
// corner weights sum to 2), so ~1e-3 offset error (bf16) flips samples.
// One block per (b,ii); 256 threads = 128 j x 2 c-halves.
// Weights scalarized via readfirstlane -> s_load.
// NEW: emits PRE-SELECTED interp weights (A,B,C,D) so k_gemm's per-channel
// combine is 4 FMAs with no cndmask selects.
// ---------------------------------------------------------------------------
__global__ __launch_bounds__(256) void k_conv_meta(
    const float* __restrict__ x, const float* __restrict__ wp,
    const float* __restrict__ bp, int* __restrict__ midx,
    float4* __restrict__ mw)
{
  int blk = swz(blockIdx.x);
  int bb = blk >> 7, ii = blk & 127;
  int tid = threadIdx.x;
  int j = tid & 127;
  int chalf = tid >> 7;     // wave-uniform (waves 0,1 -> 0; waves 2,3 -> 1)

  float acc[18];
#pragma unroll
  for (int o = 0; o < 18; ++o) acc[o] = 0.f;

  for (int c = chalf * 64; c < chalf * 64 + 64; ++c) {
    int cu = __builtin_amdgcn_readfirstlane(c);   // provably uniform
    const float* xc = x + ((size_t)bb * CIN + cu) * HWSZ;  // sgpr base
    float xv[9];
#pragma unroll
    for (int dy = 0; dy < 3; ++dy) {
      int r = ii + dy - 1;
      bool rok = ((unsigned)r < 128u);
#pragma unroll
      for (int dx = 0; dx < 3; ++dx) {
        int cc = j + dx - 1;
        bool ok = rok && ((unsigned)cc < 128u);
        xv[dy * 3 + dx] = ok ? xc[r * 128 + cc] : 0.f;   // j-coalesced
      }
    }
    const float* wr = wp + cu * 9;   // wp[o][c][tap]; uniform -> s_load
#pragma unroll
    for (int o = 0; o < 18; ++o) {
#pragma unroll
      for (int t = 0; t < 9; ++t)
        acc[o] += xv[t] * wr[o * 1152 + t];
    }
  }

  __shared__ float red[128][18];
  if (chalf == 1) {
#pragma unroll
    for (int o = 0; o < 18; ++o) red[j][o] = acc[o];
  }
  __syncthreads();
  if (chalf == 0) {
#pragma unroll
    for (int o = 0; o < 18; ++o) acc[o] += red[j][o];

#pragma unroll
    for (int n = 0; n < NP; ++n) {
      float offx = acc[n] + bp[n];
      float offy = acc[9 + n] + bp[9 + n];
      float px = (float)ii + (float)(n / 3) + offx;   // row coord (H)
      float py = (float)j  + (float)(n % 3) + offy;   // col coord (W)
      float f0 = floorf(px), f1 = f0 + 1.f;
      float h0 = floorf(py), h1 = h0 + 1.f;
      int r0 = (int)fminf(fmaxf(f0, 0.f), 127.f);
      int r1 = (int)fminf(fmaxf(f1, 0.f), 127.f);
      int c0 = (int)fminf(fmaxf(h0, 0.f), 127.f);
      int c1 = (int)fminf(fmaxf(h1, 0.f), 127.f);
      float pxc = fminf(fmaxf(px, 0.f), 127.f);
      float pyc = fminf(fmaxf(py, 0.f), 127.f);
      float glt = (1.f + ((float)r0 - pxc)) * (1.f + ((float)c0 - pyc));
      float grb = (1.f - ((float)r1 - pxc)) * (1.f - ((float)c1 - pyc));
      float glb = (1.f + ((float)r0 - pxc)) * (1.f - ((float)c1 - pyc));
      float grt = (1.f - ((float)r1 - pxc)) * (1.f + ((float)c0 - pyc));
      // pre-select: both sampled cols live in the float2 at col qb.
      // av = A*x[r0][qb] + B*x[r0][qb+1] + C*x[r1][qb] + D*x[r1][qb+1]
      int qb = (c0 < 126) ? c0 : 126;
      bool s0 = (c0 != qb), s1 = (c1 != qb);
      float wA = (s0 ? 0.f : glt) + (s1 ? 0.f : glb);
      float wB = (s0 ? glt : 0.f) + (s1 ? glb : 0.f);
      float wC = (s0 ? 0.f : grt) + (s1 ? 0.f : grb);
      float wD = (s0 ? grt : 0.f) + (s1 ? grb : 0.f);
      int base = ((bb * 128 + ii) * NP + n) * 128 + j;
      midx[base] = r0 | (r1 << 8) | (qb << 16);
      mw[base] = make_float4(wA, wB, wC, wD);
    }
  }
}

// ---------------------------------------------------------------------------
// Fused gather + GEMM. One block per (b,ii): Mtile=128 (j), Ntile=256 (o).
// 512 threads = 8 waves; wave (mh, oq) owns 64m x 64o. BK=32, double-buffered
// LDS, one barrier per chunk.
// NEW SCHEDULE (software pipeline, 1 chunk deep):
//   interp(kk) [uses regs prefetched last iter] -> ds_write A(kk)
//   decode meta(kk+1)                              (LDS, before barrier)
//   barrier                                        (drains gll B(kk))
//   issue A-gather loads(kk+1) -> regs             (land during MFMA)
//   issue B global_load_lds(kk+1) -> other buffer  (drains at next barrier)
//   ds_read frags(kk) + 16 MFMA
// This takes the ~500cyc gather/B latency off the per-chunk critical path.
// ---------------------------------------------------------------------------
__global__ __launch_bounds__(512, 4) void k_gemm(
    const float* __restrict__ x, const bf16_t* __restrict__ bt,
    const int* __restrict__ midx, const float4* __restrict__ mw,
    float* __restrict__ out)
{
  // A0 @0 (10240) | A1 @10240 | B0 @20480 (16384) | B1 @36864 | mi @53248 | mwl @57856
  __shared__ __align__(16) char smem[76288];
  int*    mi  = (int*)   (smem + 53248);
  float4* mwl = (float4*)(smem + 57856);

  int blk = swz(blockIdx.x);
  int bb = blk >> 7, ii = blk & 127;
  int tid = threadIdx.x;
  int wave = tid >> 6, lane = tid & 63;
  int l15 = lane & 15, quad = lane >> 4;
  int mh = wave & 1;
  int oq = wave >> 1;
  int jloc = mh * 64 + lane;
  int cgrp = __builtin_amdgcn_readfirstlane(oq);   // wave-uniform -> sgpr gather base

  {
    int base = (bb * 128 + ii) * (NP * 128);
    for (int t = tid; t < NP * 128; t += 512) mi[t] = midx[base + t];
    for (int t = tid; t < NP * 128; t += 512) mwl[t] = mw[base + t];
  }
  __syncthreads();

  const float* xb = x + (size_t)bb * CIN * HWSZ;

  // B source offsets (bytes): id = tid + s*512; o = id>>2; gg = id&3
  const char* btB = (const char*)bt;
  unsigned bsrc0 = (unsigned)(tid >> 2) * (KDIM * 2) + (unsigned)(tid & 3) * 16;
  unsigned bsrc1 = (unsigned)((tid + 512) >> 2) * (KDIM * 2) + (unsigned)(tid & 3) * 16;

  f32x4 acc[4][4];
#pragma unroll
  for (int mt = 0; mt < 4; ++mt)
#pragma unroll
    for (int ot = 0; ot < 4; ++ot) acc[mt][ot] = (f32x4){0.f, 0.f, 0.f, 0.f};

  // ---- prologue: decode + prefetch chunk 0
  F2 pa[8], pb[8];
  float4 wv;
  {
    int idx = mi[jloc];                 // n=0
    wv = mwl[jloc];
    int r0 = idx & 255, r1 = (idx >> 8) & 255, qb = (idx >> 16) & 255;
    int oA = (r0 << 7) + qb, oB = (r1 << 7) + qb;
    const float* xc = xb + (size_t)(cgrp * 8) * HWSZ;   // c0=0
#pragma unroll
    for (int it = 0; it < 8; ++it) {
      pa[it] = *(const F2*)(xc + it * HWSZ + oA);
      pb[it] = *(const F2*)(xc + it * HWSZ + oB);
    }
    gll16(btB + bsrc0, smem + 20480 + tid * 16);
    gll16(btB + bsrc1, smem + 20480 + tid * 16 + 8192);
  }

#pragma unroll 1
  for (int kk = 0; kk < 36; ++kk) {
    int cur = kk & 1;
    bf16_t* Ald = (bf16_t*)(smem + cur * 10240);

    // ---- interp chunk kk from prefetched regs: 4 FMAs/channel, no selects
    bf16x8 av;
#pragma unroll
    for (int it = 0; it < 8; ++it) {
      float v = wv.x * pa[it].x + wv.y * pa[it].y
              + wv.z * pb[it].x + wv.w * pb[it].y;
      av[it] = (bf16_t)v;
    }
    *(bf16x8*)(Ald + jloc * 40 + cgrp * 8) = av;

    // ---- decode meta for kk+1 (meta LDS is never overwritten -> safe pre-barrier)
    int oA2 = 0, oB2 = 0;
    float4 wv2 = wv;
    if (kk < 35) {
      int n2 = (kk + 1) >> 2;
      int idx2 = mi[n2 * 128 + jloc];
      wv2 = mwl[n2 * 128 + jloc];
      int r0 = idx2 & 255, r1 = (idx2 >> 8) & 255, qb = (idx2 >> 16) & 255;
      oA2 = (r0 << 7) + qb;
      oB2 = (r1 << 7) + qb;
    }

    __syncthreads();   // A(kk) written; gll B(kk) drained (vmcnt0 at barrier)

    // ---- prefetch chunk kk+1 (lands under the MFMAs below)
    if (kk < 35) {
      int c0n = ((kk + 1) & 3) * 32;
      const float* xc2 = xb + (size_t)(c0n + cgrp * 8) * HWSZ;
#pragma unroll
      for (int it = 0; it < 8; ++it) {
        pa[it] = *(const F2*)(xc2 + it * HWSZ + oA2);
        pb[it] = *(const F2*)(xc2 + it * HWSZ + oB2);
      }
      char* Bn = smem + 20480 + ((kk + 1) & 1) * 16384;
      gll16(btB + bsrc0 + (unsigned)(kk + 1) * 64, Bn + tid * 16);
      gll16(btB + bsrc1 + (unsigned)(kk + 1) * 64, Bn + tid * 16 + 8192);
    }
    wv = wv2;

    // ---- fragments + MFMA (af per-mt to keep live regs under the 128 cap)
    bf16_t* Bld = (bf16_t*)(smem + 20480 + cur * 16384);
    bf16x8 bfr[4];
#pragma unroll
    for (int ot = 0; ot < 4; ++ot)
      bfr[ot] = *(bf16x8*)(Bld + (oq * 64 + ot * 16 + l15) * 32 + quad * 8);
#pragma unroll
    for (int mt = 0; mt < 4; ++mt) {
      bf16x8 af = *(bf16x8*)(Ald + (mh * 64 + mt * 16 + l15) * 40 + quad * 8);
#pragma unroll
      for (int ot = 0; ot < 4; ++ot)
        acc[mt][ot] = __builtin_amdgcn_mfma_f32_16x16x32_bf16(
            af, bfr[ot], acc[mt][ot], 0, 0, 0);
    }
  }

  // ---- epilogue: transpose 32-o x 128-j pieces through LDS, coalesced stores
  float* piece = (float*)smem;   // 32 x 132 floats
  for (int p = 0; p < 8; ++p) {
    __syncthreads();
    if (oq == (p >> 1)) {
      int otbase = (p & 1) * 2;
#pragma unroll
      for (int t2 = 0; t2 < 2; ++t2) {
        int ot = otbase + t2;
        int o_ip = t2 * 16 + l15;
#pragma unroll
        for (int mt = 0; mt < 4; ++mt) {
          int jj = mh * 64 + mt * 16 + quad * 4;
          *(f32x4*)(piece + o_ip * 132 + jj) = acc[mt][ot];
        }
      }
    }
    __syncthreads();
#pragma unroll
    for (int s = 0; s < 2; ++s) {
      int id = tid + s * 512;
      int o_ip = id >> 5, part = id & 31;
      f32x4 v = *(f32x4*)(piece + o_ip * 132 + part * 4);
      *(f32x4*)(out + (((size_t)bb * OCH + p * 32 + o_ip) * 128 + ii) * 128 + part * 4) = v;
    }
  }
}

// ---------------------------------------------------------------------------
extern "C" void kernel_launch(void* const* d_in, const int* in_sizes, int n_in,
                              void* d_out, int out_size, void* d_ws, size_t ws_size,
                              hipStream_t stream) {
  const float* x  = (const float*)d_in[0];
  const float* wp = (const float*)d_in[1];
  const float* bp = (const float*)d_in[2];
  const float* wc = (const float*)d_in[3];
  float* out = (float*)d_out;

  bf16_t* BT   = (bf16_t*)d_ws;                              // 589,824 B
  int*    MIDX = (int*)   ((char*)d_ws + (1u << 20));        // 2,359,296 B
  float4* MW   = (float4*)((char*)d_ws + (4u << 20));        // 9,437,184 B

  k_bt<<<dim3(9, 256), 128, 0, stream>>>(wc, BT);
  k_conv_meta<<<512, 256, 0, stream>>>(x, wp, bp, MIDX, MW);
  k_gemm<<<512, 512, 0, stream>>>(x, BT, MIDX, MW, out);
}